// Round 2
// baseline (12.406 us; speedup 1.0000x reference)
//
#include <hip/hip_runtime.h>

// Output row (b,i): [ exp(-((xi4-xj4)^2+(xi5-xj5)^2)) for j in 0..511 | x[b,i,10:20] | 30 zeros ]
// = 552 floats. x shape (8, 512, 20) fp32. Row stride 2208 B (16B-aligned).

#define GS    512
#define TWO_P 20
#define P     10
#define FREE  30
#define ROWW  (GS + P + FREE)   // 552
#define TPB   128

__global__ __launch_bounds__(TPB) void gbuilder_kernel(const float* __restrict__ x,
                                                       float* __restrict__ out) {
    const int row = blockIdx.x;          // b*512 + i
    const int b   = row >> 9;
    const int i   = row & (GS - 1);
    const int t   = threadIdx.x;

    const float* xb = x + (size_t)b * GS * TWO_P;

    // Broadcast read of row i's metric coords (cols 4,5 adjacent, 8B-aligned).
    const float2 xi = *reinterpret_cast<const float2*>(xb + i * TWO_P + 4);

    // Each thread computes 4 adjacent j's and stores one float4.
    const int j0 = 4 * t;
    float4 r;
    #pragma unroll
    for (int k = 0; k < 4; ++k) {
        const float2 xj = *reinterpret_cast<const float2*>(xb + (j0 + k) * TWO_P + 4);
        const float d4 = xi.x - xj.x;
        const float d5 = xi.y - xj.y;
        (&r.x)[k] = __expf(-(d4 * d4 + d5 * d5));
    }

    float* orow = out + (size_t)row * ROWW;
    *reinterpret_cast<float4*>(orow + j0) = r;

    // Tail: elements 512..551 = 10 parax + 30 zeros = 10 float4 stores (16B-aligned).
    if (t < 10) {
        float4 tail = make_float4(0.f, 0.f, 0.f, 0.f);
        const float* xi_row = xb + i * TWO_P;
        if (t == 0) {
            tail.x = xi_row[10]; tail.y = xi_row[11]; tail.z = xi_row[12]; tail.w = xi_row[13];
        } else if (t == 1) {
            tail.x = xi_row[14]; tail.y = xi_row[15]; tail.z = xi_row[16]; tail.w = xi_row[17];
        } else if (t == 2) {
            tail.x = xi_row[18]; tail.y = xi_row[19];
        }
        *reinterpret_cast<float4*>(orow + GS + 4 * t) = tail;
    }
}

extern "C" void kernel_launch(void* const* d_in, const int* in_sizes, int n_in,
                              void* d_out, int out_size, void* d_ws, size_t ws_size,
                              hipStream_t stream) {
    const float* x = (const float*)d_in[0];
    float* out = (float*)d_out;
    gbuilder_kernel<<<8 * GS, TPB, 0, stream>>>(x, out);
}

// Round 3
// 10.456 us; speedup vs baseline: 1.1865x; 1.1865x over previous
//
#include <hip/hip_runtime.h>

// Output row (b,i): [ exp(-((xi4-xj4)^2+(xi5-xj5)^2)) for j=0..511 | x[b,i,10:20] | 30 zeros ]
// = 552 floats. x shape (8, 512, 20) fp32. Row stride 2208 B.
// Grid: 512 blocks x 256 threads; each block does 8 rows (64 blocks/batch, no batch crossing).
// Thread t: row r = t>>5, j-set = {(t&31)*4 + 128*q + k : q=0..3, k=0..3}.
// Store q is 16B/lane contiguous across the 32 lanes of a row-group.

#define GS    512
#define TWO_P 20
#define P     10
#define ROWW  (GS + P + 30)   // 552
#define TPB   256
#define RPB   8               // rows per block

__global__ __launch_bounds__(TPB) void gbuilder_kernel(const float* __restrict__ x,
                                                       float* __restrict__ out) {
    const int row0 = blockIdx.x * RPB;        // first row (global, b*512+i)
    const int b    = row0 >> 9;
    const int t    = threadIdx.x;

    const float* xb = x + (size_t)b * GS * TWO_P;

    const int r  = t >> 5;                    // 0..7: which of the block's 8 rows
    const int i  = (row0 & (GS - 1)) + r;     // row index within batch
    const float2 xi = *reinterpret_cast<const float2*>(xb + i * TWO_P + 4);

    float* orow = out + (size_t)(row0 + r) * ROWW;
    const int jb = (t & 31) * 4;              // lane's base j within each 128-chunk

    #pragma unroll
    for (int q = 0; q < 4; ++q) {
        float4 v;
        #pragma unroll
        for (int k = 0; k < 4; ++k) {
            const int j = jb + 128 * q + k;
            const float2 xj = *reinterpret_cast<const float2*>(xb + j * TWO_P + 4);
            const float d4 = xi.x - xj.x;
            const float d5 = xi.y - xj.y;
            (&v.x)[k] = __expf(-(d4 * d4 + d5 * d5));
        }
        *reinterpret_cast<float4*>(orow + jb + 128 * q) = v;
    }

    // Tail: per row, elements 512..551 = 10 parax + 30 zeros = 10 float4 stores.
    // 8 rows x 10 slots = 80 threads.
    if (t < 80) {
        const int rr = t / 10;
        const int s  = t % 10;
        const int ii = (row0 & (GS - 1)) + rr;
        const float* xrow = xb + ii * TWO_P;
        float4 tail = make_float4(0.f, 0.f, 0.f, 0.f);
        #pragma unroll
        for (int q = 0; q < 4; ++q) {
            const int m = 4 * s + q;
            if (m < P) (&tail.x)[q] = xrow[P + m];
        }
        *reinterpret_cast<float4*>(out + (size_t)(row0 + rr) * ROWW + GS + 4 * s) = tail;
    }
}

extern "C" void kernel_launch(void* const* d_in, const int* in_sizes, int n_in,
                              void* d_out, int out_size, void* d_ws, size_t ws_size,
                              hipStream_t stream) {
    const float* x = (const float*)d_in[0];
    float* out = (float*)d_out;
    gbuilder_kernel<<<(8 * GS) / RPB, TPB, 0, stream>>>(x, out);
}